// Round 1
// baseline (341.382 us; speedup 1.0000x reference)
//
#include <hip/hip_runtime.h>
#include <math.h>

#define Bdim 8
#define Cdim 128
#define Ndim 16384
#define Kdim 8

// ---------------- kernel 1: bin assignment + counts ----------------
__global__ void __launch_bounds__(256) k_bin(const float* __restrict__ logits,
                                             signed char* __restrict__ kbin,
                                             int* __restrict__ cnt) {
  __shared__ int h[Kdim];
  int tid = threadIdx.x;
  if (tid < Kdim) h[tid] = 0;
  __syncthreads();
  int idx = blockIdx.x * 256 + tid;              // < B*N, block stays in one b
  int b = idx >> 14;                             // /16384
  float w = tanhf(logits[idx]);
  int kb = -1;
#pragma unroll
  for (int j = 0; j < Kdim; ++j) {
    float lo = -1.0f + 0.25f * (float)j;
    float hi = lo + 0.25f;
    if (w > lo && w <= hi && w != 0.0f) kb = j;
  }
  kbin[idx] = (signed char)kb;
  if (kb >= 0) atomicAdd(&h[kb], 1);
  __syncthreads();
  if (tid < Kdim) atomicAdd(&cnt[b * Kdim + tid], h[tid]);
}

// ---------------- kernel 2: per-(b,c) masked pooling + masked sum of squares ----
__global__ void __launch_bounds__(256) k_pool(const float* __restrict__ x,
                                              const signed char* __restrict__ kbin,
                                              float* __restrict__ pooled,
                                              float* __restrict__ sxx) {
  int bc = blockIdx.x;                 // b*C + c
  int b = bc >> 7;
  const float4* xr = (const float4*)(x + (size_t)bc * Ndim);
  const char4* kr = (const char4*)(kbin + b * Ndim);
  float acc[Kdim];
#pragma unroll
  for (int j = 0; j < Kdim; ++j) acc[j] = 0.f;
  float s2 = 0.f;
  int tid = threadIdx.x;
  for (int n4 = tid; n4 < Ndim / 4; n4 += 256) {
    float4 v = xr[n4];
    char4 kb = kr[n4];
    float ve[4] = {v.x, v.y, v.z, v.w};
    signed char ke[4] = {kb.x, kb.y, kb.z, kb.w};
#pragma unroll
    for (int e = 0; e < 4; ++e) {
      float xv = ve[e];
      int kv = ke[e];
      if (kv >= 0) s2 += xv * xv;
#pragma unroll
      for (int j = 0; j < Kdim; ++j) acc[j] += (kv == j) ? xv : 0.f;  // no runtime-indexed array (scratch!)
    }
  }
#pragma unroll
  for (int off = 32; off > 0; off >>= 1) {
#pragma unroll
    for (int j = 0; j < Kdim; ++j) acc[j] += __shfl_down(acc[j], off);
    s2 += __shfl_down(s2, off);
  }
  __shared__ float red[4][Kdim + 1];
  int wv = tid >> 6, ln = tid & 63;
  if (ln == 0) {
#pragma unroll
    for (int j = 0; j < Kdim; ++j) red[wv][j] = acc[j];
    red[wv][Kdim] = s2;
  }
  __syncthreads();
  if (tid < Kdim) pooled[bc * Kdim + tid] = red[0][tid] + red[1][tid] + red[2][tid] + red[3][tid];
  if (tid == Kdim) sxx[bc] = red[0][Kdim] + red[1][Kdim] + red[2][Kdim] + red[3][Kdim];
}

// ---------------- kernel 3: 3-layer transformer + closed-form norm stats -------
__global__ void __launch_bounds__(256) k_xform(
    const float* __restrict__ pooled, const int* __restrict__ cnt,
    const float* __restrict__ sxx,
    const float* __restrict__ Wq1, const float* __restrict__ Wk1, const float* __restrict__ Wv1,
    const float* __restrict__ Wq2, const float* __restrict__ Wk2, const float* __restrict__ Wv2,
    const float* __restrict__ Wq3, const float* __restrict__ Wk3, const float* __restrict__ Wv3,
    const float* __restrict__ ln_w, const float* __restrict__ ln_b,
    float* __restrict__ feat, float* __restrict__ mu_i, float* __restrict__ rs_i,
    float* __restrict__ ratio) {
  __shared__ float f_l[Kdim][Cdim], q_l[Kdim][Cdim], kk_l[Kdim][Cdim], v_l[Kdim][Cdim];
  __shared__ float s_l[Cdim][Cdim];
  __shared__ float cnt_raw[Kdim], cnt_div[Kdim];
  int b = blockIdx.x, tid = threadIdx.x;
  if (tid < Kdim) {
    int cc = cnt[b * Kdim + tid];
    cnt_raw[tid] = (float)cc;
    cnt_div[tid] = (float)(cc == 0 ? 1 : cc);
  }
  __syncthreads();
  for (int idx = tid; idx < Cdim * Kdim; idx += 256) {
    int c = idx >> 3, j = idx & 7;
    f_l[j][c] = pooled[(b * Cdim + c) * Kdim + j] / cnt_div[j];
  }
  const float* Wq[3] = {Wq1, Wq2, Wq3};
  const float* Wk[3] = {Wk1, Wk2, Wk3};
  const float* Wv[3] = {Wv1, Wv2, Wv3};
  const float inv_temp = 0.08838834764831845f;  // 1/sqrt(128)
  for (int layer = 0; layer < 3; ++layer) {
    __syncthreads();
    for (int idx = tid; idx < Cdim * Kdim; idx += 256) {
      int c = idx >> 3, j = idx & 7;
      const float* wq = Wq[layer] + c * Cdim;
      const float* wk = Wk[layer] + c * Cdim;
      const float* wv = Wv[layer] + c * Cdim;
      float aq = 0.f, ak = 0.f, av = 0.f;
      for (int d = 0; d < Cdim; ++d) {
        float fv = f_l[j][d];
        aq = fmaf(wq[d], fv, aq);
        ak = fmaf(wk[d], fv, ak);
        av = fmaf(wv[d], fv, av);
      }
      q_l[j][c] = aq * inv_temp;
      kk_l[j][c] = ak;
      v_l[j][c] = av;
    }
    __syncthreads();
    for (int idx = tid; idx < Cdim * Cdim; idx += 256) {
      int c = idx >> 7, d = idx & 127;
      float s = 0.f;
#pragma unroll
      for (int j = 0; j < Kdim; ++j) s = fmaf(q_l[j][c], kk_l[j][d], s);
      s_l[c][d] = s;
    }
    __syncthreads();
    if (tid < Cdim) {
      float m = -1e30f;
      for (int d = 0; d < Cdim; ++d) m = fmaxf(m, s_l[tid][d]);
      float sum = 0.f;
      for (int d = 0; d < Cdim; ++d) {
        float e = expf(s_l[tid][d] - m);
        s_l[tid][d] = e;
        sum += e;
      }
      float r = 1.f / sum;
      for (int d = 0; d < Cdim; ++d) s_l[tid][d] *= r;
    }
    __syncthreads();
    for (int idx = tid; idx < Cdim * Kdim; idx += 256) {
      int c = idx >> 3, j = idx & 7;
      float o = 0.f;
      for (int d = 0; d < Cdim; ++d) o = fmaf(s_l[c][d], v_l[j][d], o);
      q_l[j][c] = o + f_l[j][c];  // residual, reuse q_l as t
    }
    __syncthreads();
    if (tid < Kdim) {
      int j = tid;
      float mu = 0.f;
      for (int c = 0; c < Cdim; ++c) mu += q_l[j][c];
      mu *= (1.f / Cdim);
      float var = 0.f;
      for (int c = 0; c < Cdim; ++c) {
        float d = q_l[j][c] - mu;
        var += d * d;
      }
      var *= (1.f / Cdim);
      float rs = rsqrtf(var + 1e-6f);
      for (int c = 0; c < Cdim; ++c) f_l[j][c] = (q_l[j][c] - mu) * rs * ln_w[c] + ln_b[c];
    }
  }
  __syncthreads();
  if (tid < Cdim) {
    int c = tid;
    float S1 = 0.f, S2c = 0.f;
#pragma unroll
    for (int j = 0; j < Kdim; ++j) {
      float pl = pooled[(b * Cdim + c) * Kdim + j];
      float fe = f_l[j][c];
      feat[(b * Cdim + c) * Kdim + j] = fe;
      S1 += pl + cnt_raw[j] * fe;
      S2c += 2.f * pl * fe + cnt_raw[j] * fe * fe;
    }
    float S2 = sxx[b * Cdim + c] + S2c;
    float mu = S1 * (1.f / Ndim);
    float var = S2 * (1.f / Ndim) - mu * mu;
    float rs = rsqrtf(var + 1e-5f);
    mu_i[b * Cdim + c] = mu;
    rs_i[b * Cdim + c] = rs;
    ratio[b * Cdim + c] = var * rs * rs;  // var/(var+eps) for batch-norm var
  }
}

// ---------------- kernel 4: fold instance+batch norm into per-(b,c) affine -----
__global__ void k_alpha(const float* __restrict__ mu_i, const float* __restrict__ rs_i,
                        const float* __restrict__ ratio, const float* __restrict__ bn_w,
                        const float* __restrict__ bn_b, float* __restrict__ alpha,
                        float* __restrict__ beta) {
  int c = threadIdx.x;  // 128 threads, 1 block
  float vb = 0.f;
  for (int b = 0; b < Bdim; ++b) vb += ratio[b * Cdim + c];
  vb *= (1.f / Bdim);
  float rsb = rsqrtf(vb + 1e-5f);   // batch-norm mean is exactly 0
  float w = bn_w[c], bb = bn_b[c];
  for (int b = 0; b < Bdim; ++b) {
    float a = rs_i[b * Cdim + c] * rsb * w;
    alpha[b * Cdim + c] = a;
    beta[b * Cdim + c] = bb - mu_i[b * Cdim + c] * a;
  }
}

// ---------------- kernel 5: transpose conv0_w once -----------------------------
__global__ void k_transpose(const float* __restrict__ W, float* __restrict__ Wt) {
  int idx = blockIdx.x * 256 + threadIdx.x;  // 16384
  int o = idx >> 7, c = idx & 127;
  Wt[c * Cdim + o] = W[idx];
}

// ---------------- kernel 6: fused recon+norm+gelu+conv (main pass) -------------
__global__ void __launch_bounds__(256) k_conv(
    const float* __restrict__ x, const signed char* __restrict__ kbin,
    const float* __restrict__ feat, const float* __restrict__ alpha,
    const float* __restrict__ beta, const float* __restrict__ Wt,
    const float* __restrict__ bias, float* __restrict__ out,
    float* __restrict__ partial) {
  __shared__ float Wl[Cdim][Cdim];   // W transposed: Wl[c][o]
  __shared__ float g_l[Cdim][Cdim];  // activations: g_l[c][n_local]
  __shared__ float feat_l[Cdim][Kdim];
  __shared__ float al_l[Cdim], be_l[Cdim];
  __shared__ signed char kb_l[128];
  int bx = blockIdx.x;
  int b = bx >> 7, nb = bx & 127;
  int n0 = nb * 128;
  int tid = threadIdx.x;
  for (int i4 = tid; i4 < Cdim * Cdim / 4; i4 += 256)
    ((float4*)Wl)[i4] = ((const float4*)Wt)[i4];
  for (int idx = tid; idx < Cdim * Kdim; idx += 256)
    ((float*)feat_l)[idx] = feat[b * Cdim * Kdim + idx];
  if (tid < Cdim) {
    al_l[tid] = alpha[b * Cdim + tid];
    be_l[tid] = beta[b * Cdim + tid];
  }
  if (tid < 128) kb_l[tid] = kbin[b * Ndim + n0 + tid];
  __syncthreads();
  // stage gelu'd activations
  for (int idx = tid; idx < Cdim * 32; idx += 256) {
    int c = idx >> 5, q4 = idx & 31;
    float4 xv = *(const float4*)(x + ((size_t)(b * Cdim + c)) * Ndim + n0 + q4 * 4);
    float a = al_l[c], be = be_l[c];
    float xe[4] = {xv.x, xv.y, xv.z, xv.w};
    float r[4];
#pragma unroll
    for (int e = 0; e < 4; ++e) {
      int kb = kb_l[q4 * 4 + e];
      float rec = (kb >= 0) ? (xe[e] + feat_l[c][kb]) : 0.0f;
      float h = fmaf(a, rec, be);
      r[e] = 0.5f * h * (1.0f + erff(h * 0.7071067811865475244f));
    }
    *(float4*)&g_l[c][q4 * 4] = make_float4(r[0], r[1], r[2], r[3]);
  }
  __syncthreads();
  int tx = tid & 15, ty = tid >> 4;
  float acc[8][8];
#pragma unroll
  for (int i = 0; i < 8; ++i)
#pragma unroll
    for (int j = 0; j < 8; ++j) acc[i][j] = 0.f;
#pragma unroll 4
  for (int c = 0; c < Cdim; ++c) {
    float4 a0 = *(const float4*)&Wl[c][ty * 8];
    float4 a1 = *(const float4*)&Wl[c][ty * 8 + 4];
    float4 b0 = *(const float4*)&g_l[c][tx * 4];
    float4 b1 = *(const float4*)&g_l[c][tx * 4 + 64];
    float av[8] = {a0.x, a0.y, a0.z, a0.w, a1.x, a1.y, a1.z, a1.w};
    float bv[8] = {b0.x, b0.y, b0.z, b0.w, b1.x, b1.y, b1.z, b1.w};
#pragma unroll
    for (int i = 0; i < 8; ++i)
#pragma unroll
      for (int j = 0; j < 8; ++j) acc[i][j] = fmaf(av[i], bv[j], acc[i][j]);
  }
#pragma unroll
  for (int i = 0; i < 8; ++i) {
    int o = ty * 8 + i;
    float bo = bias[o];
#pragma unroll
    for (int j = 0; j < 8; ++j) acc[i][j] += bo;
    float* orow = out + ((size_t)(b * Cdim + o)) * Ndim + n0;
    *(float4*)(orow + tx * 4) = make_float4(acc[i][0], acc[i][1], acc[i][2], acc[i][3]);
    *(float4*)(orow + 64 + tx * 4) = make_float4(acc[i][4], acc[i][5], acc[i][6], acc[i][7]);
    float s = 0.f;
#pragma unroll
    for (int j = 0; j < 8; ++j) s += acc[i][j];
    s += __shfl_xor(s, 1);
    s += __shfl_xor(s, 2);
    s += __shfl_xor(s, 4);
    s += __shfl_xor(s, 8);
    if (tx == 0) partial[bx * 128 + o] = s;
  }
}

// ---------------- kernel 7: SE MLP ---------------------------------------------
__global__ void __launch_bounds__(128) k_mlp(const float* __restrict__ partial,
                                             const float* __restrict__ fc1w,
                                             const float* __restrict__ fc1b,
                                             const float* __restrict__ fc2w,
                                             const float* __restrict__ fc2b,
                                             float* __restrict__ f2g) {
  __shared__ float sq[Cdim];
  __shared__ float f1[64];
  int b = blockIdx.x, tid = threadIdx.x;  // 128 threads
  float s = 0.f;
  for (int nb = 0; nb < 128; ++nb) s += partial[(b * 128 + nb) * 128 + tid];
  sq[tid] = s * (1.0f / Ndim);
  __syncthreads();
  if (tid < 64) {
    float a = fc1b[tid];
    for (int c = 0; c < Cdim; ++c) a = fmaf(fc1w[tid * Cdim + c], sq[c], a);
    f1[tid] = 0.5f * a * (1.0f + erff(a * 0.7071067811865475244f));
  }
  __syncthreads();
  float a2 = fc2b[tid];
  for (int i = 0; i < 64; ++i) a2 = fmaf(fc2w[tid * 64 + i], f1[i], a2);
  f2g[b * Cdim + tid] = 1.0f / (1.0f + expf(-a2));
}

// ---------------- kernel 8: apply SE scale in place ----------------------------
__global__ void __launch_bounds__(256) k_scale(float* __restrict__ out,
                                               const float* __restrict__ f2g) {
  size_t stride = (size_t)gridDim.x * blockDim.x;
  size_t tot = (size_t)Bdim * Cdim * Ndim / 4;
  for (size_t i4 = (size_t)blockIdx.x * 256 + threadIdx.x; i4 < tot; i4 += stride) {
    int bc = (int)(i4 >> 12);  // (i4*4)/16384
    float m = f2g[bc];
    float4 v = ((float4*)out)[i4];
    v.x *= m; v.y *= m; v.z *= m; v.w *= m;
    ((float4*)out)[i4] = v;
  }
}

extern "C" void kernel_launch(void* const* d_in, const int* in_sizes, int n_in,
                              void* d_out, int out_size, void* d_ws, size_t ws_size,
                              hipStream_t stream) {
  const float* x = (const float*)d_in[0];
  const float* logits = (const float*)d_in[1];
  const float* Wq1 = (const float*)d_in[2];
  const float* Wk1 = (const float*)d_in[3];
  const float* Wv1 = (const float*)d_in[4];
  const float* Wq2 = (const float*)d_in[5];
  const float* Wk2 = (const float*)d_in[6];
  const float* Wv2 = (const float*)d_in[7];
  const float* Wq3 = (const float*)d_in[8];
  const float* Wk3 = (const float*)d_in[9];
  const float* Wv3 = (const float*)d_in[10];
  const float* ln_w = (const float*)d_in[11];
  const float* ln_b = (const float*)d_in[12];
  const float* conv0_w = (const float*)d_in[13];
  const float* conv0_b = (const float*)d_in[14];
  const float* bn_w = (const float*)d_in[15];
  const float* bn_b = (const float*)d_in[16];
  const float* fc1_w = (const float*)d_in[17];
  const float* fc1_b = (const float*)d_in[18];
  const float* fc2_w = (const float*)d_in[19];
  const float* fc2_b = (const float*)d_in[20];
  float* out = (float*)d_out;

  char* p = (char*)d_ws;
  auto alloc = [&](size_t bytes) {
    char* r = p;
    p += (bytes + 255) & ~(size_t)255;
    return r;
  };
  signed char* kbin = (signed char*)alloc(Bdim * Ndim);
  int* cnt = (int*)alloc(Bdim * Kdim * 4);
  float* pooled = (float*)alloc(Bdim * Cdim * Kdim * 4);
  float* sxx = (float*)alloc(Bdim * Cdim * 4);
  float* feat = (float*)alloc(Bdim * Cdim * Kdim * 4);
  float* mu_i = (float*)alloc(Bdim * Cdim * 4);
  float* rs_i = (float*)alloc(Bdim * Cdim * 4);
  float* ratio = (float*)alloc(Bdim * Cdim * 4);
  float* alpha = (float*)alloc(Bdim * Cdim * 4);
  float* beta = (float*)alloc(Bdim * Cdim * 4);
  float* Wt = (float*)alloc(Cdim * Cdim * 4);
  float* f2g = (float*)alloc(Bdim * Cdim * 4);
  float* partial = (float*)alloc((size_t)Bdim * 128 * 128 * 4);

  hipMemsetAsync(cnt, 0, Bdim * Kdim * sizeof(int), stream);
  k_bin<<<Bdim * Ndim / 256, 256, 0, stream>>>(logits, kbin, cnt);
  k_transpose<<<Cdim * Cdim / 256, 256, 0, stream>>>(conv0_w, Wt);
  k_pool<<<Bdim * Cdim, 256, 0, stream>>>(x, kbin, pooled, sxx);
  k_xform<<<Bdim, 256, 0, stream>>>(pooled, cnt, sxx, Wq1, Wk1, Wv1, Wq2, Wk2, Wv2,
                                    Wq3, Wk3, Wv3, ln_w, ln_b, feat, mu_i, rs_i, ratio);
  k_alpha<<<1, 128, 0, stream>>>(mu_i, rs_i, ratio, bn_w, bn_b, alpha, beta);
  k_conv<<<Bdim * (Ndim / 128), 256, 0, stream>>>(x, kbin, feat, alpha, beta, Wt,
                                                  conv0_b, out, partial);
  k_mlp<<<Bdim, 128, 0, stream>>>(partial, fc1_w, fc1_b, fc2_w, fc2_b, f2g);
  k_scale<<<2048, 256, 0, stream>>>(out, f2g);
}

// Round 2
// 287.643 us; speedup vs baseline: 1.1868x; 1.1868x over previous
//
#include <hip/hip_runtime.h>
#include <math.h>

#define Bdim 8
#define Cdim 128
#define Ndim 16384
#define Kdim 8

// ---------------- kernel 1: bin assignment + counts ----------------
__global__ void __launch_bounds__(256) k_bin(const float* __restrict__ logits,
                                             signed char* __restrict__ kbin,
                                             int* __restrict__ cnt) {
  __shared__ int h[Kdim];
  int tid = threadIdx.x;
  if (tid < Kdim) h[tid] = 0;
  __syncthreads();
  int idx = blockIdx.x * 256 + tid;              // < B*N, block stays in one b
  int b = idx >> 14;                             // /16384
  float w = tanhf(logits[idx]);
  int kb = -1;
#pragma unroll
  for (int j = 0; j < Kdim; ++j) {
    float lo = -1.0f + 0.25f * (float)j;
    float hi = lo + 0.25f;
    if (w > lo && w <= hi && w != 0.0f) kb = j;
  }
  kbin[idx] = (signed char)kb;
  if (kb >= 0) atomicAdd(&h[kb], 1);
  __syncthreads();
  if (tid < Kdim) atomicAdd(&cnt[b * Kdim + tid], h[tid]);
}

// ---------------- kernel 2: per-(b,c) masked pooling + masked sum of squares ----
__global__ void __launch_bounds__(256) k_pool(const float* __restrict__ x,
                                              const signed char* __restrict__ kbin,
                                              float* __restrict__ pooled,
                                              float* __restrict__ sxx) {
  int bc = blockIdx.x;                 // b*C + c
  int b = bc >> 7;
  const float4* xr = (const float4*)(x + (size_t)bc * Ndim);
  const char4* kr = (const char4*)(kbin + b * Ndim);
  float acc[Kdim];
#pragma unroll
  for (int j = 0; j < Kdim; ++j) acc[j] = 0.f;
  float s2 = 0.f;
  int tid = threadIdx.x;
  for (int n4 = tid; n4 < Ndim / 4; n4 += 256) {
    float4 v = xr[n4];
    char4 kb = kr[n4];
    float ve[4] = {v.x, v.y, v.z, v.w};
    signed char ke[4] = {kb.x, kb.y, kb.z, kb.w};
#pragma unroll
    for (int e = 0; e < 4; ++e) {
      float xv = ve[e];
      int kv = ke[e];
      if (kv >= 0) s2 += xv * xv;
#pragma unroll
      for (int j = 0; j < Kdim; ++j) acc[j] += (kv == j) ? xv : 0.f;
    }
  }
#pragma unroll
  for (int off = 32; off > 0; off >>= 1) {
#pragma unroll
    for (int j = 0; j < Kdim; ++j) acc[j] += __shfl_down(acc[j], off);
    s2 += __shfl_down(s2, off);
  }
  __shared__ float red[4][Kdim + 1];
  int wv = tid >> 6, ln = tid & 63;
  if (ln == 0) {
#pragma unroll
    for (int j = 0; j < Kdim; ++j) red[wv][j] = acc[j];
    red[wv][Kdim] = s2;
  }
  __syncthreads();
  if (tid < Kdim) pooled[bc * Kdim + tid] = red[0][tid] + red[1][tid] + red[2][tid] + red[3][tid];
  if (tid == Kdim) sxx[bc] = red[0][Kdim] + red[1][Kdim] + red[2][Kdim] + red[3][Kdim];
}

// ---------------- kernel 3: 3-layer transformer + closed-form norm stats -------
__global__ void __launch_bounds__(256) k_xform(
    const float* __restrict__ pooled, const int* __restrict__ cnt,
    const float* __restrict__ sxx,
    const float* __restrict__ Wq1, const float* __restrict__ Wk1, const float* __restrict__ Wv1,
    const float* __restrict__ Wq2, const float* __restrict__ Wk2, const float* __restrict__ Wv2,
    const float* __restrict__ Wq3, const float* __restrict__ Wk3, const float* __restrict__ Wv3,
    const float* __restrict__ ln_w, const float* __restrict__ ln_b,
    float* __restrict__ feat, float* __restrict__ mu_i, float* __restrict__ rs_i,
    float* __restrict__ ratio) {
  __shared__ float f_l[Kdim][Cdim], q_l[Kdim][Cdim], kk_l[Kdim][Cdim], v_l[Kdim][Cdim];
  __shared__ float s_l[Cdim][Cdim];
  __shared__ float cnt_raw[Kdim], cnt_div[Kdim];
  int b = blockIdx.x, tid = threadIdx.x;
  if (tid < Kdim) {
    int cc = cnt[b * Kdim + tid];
    cnt_raw[tid] = (float)cc;
    cnt_div[tid] = (float)(cc == 0 ? 1 : cc);
  }
  __syncthreads();
  for (int idx = tid; idx < Cdim * Kdim; idx += 256) {
    int c = idx >> 3, j = idx & 7;
    f_l[j][c] = pooled[(b * Cdim + c) * Kdim + j] / cnt_div[j];
  }
  const float* Wq[3] = {Wq1, Wq2, Wq3};
  const float* Wk[3] = {Wk1, Wk2, Wk3};
  const float* Wv[3] = {Wv1, Wv2, Wv3};
  const float inv_temp = 0.08838834764831845f;  // 1/sqrt(128)
  for (int layer = 0; layer < 3; ++layer) {
    __syncthreads();
    for (int idx = tid; idx < Cdim * Kdim; idx += 256) {
      int c = idx >> 3, j = idx & 7;
      const float* wq = Wq[layer] + c * Cdim;
      const float* wk = Wk[layer] + c * Cdim;
      const float* wv = Wv[layer] + c * Cdim;
      float aq = 0.f, ak = 0.f, av = 0.f;
      for (int d = 0; d < Cdim; ++d) {
        float fv = f_l[j][d];
        aq = fmaf(wq[d], fv, aq);
        ak = fmaf(wk[d], fv, ak);
        av = fmaf(wv[d], fv, av);
      }
      q_l[j][c] = aq * inv_temp;
      kk_l[j][c] = ak;
      v_l[j][c] = av;
    }
    __syncthreads();
    for (int idx = tid; idx < Cdim * Cdim; idx += 256) {
      int c = idx >> 7, d = idx & 127;
      float s = 0.f;
#pragma unroll
      for (int j = 0; j < Kdim; ++j) s = fmaf(q_l[j][c], kk_l[j][d], s);
      s_l[c][d] = s;
    }
    __syncthreads();
    if (tid < Cdim) {
      float m = -1e30f;
      for (int d = 0; d < Cdim; ++d) m = fmaxf(m, s_l[tid][d]);
      float sum = 0.f;
      for (int d = 0; d < Cdim; ++d) {
        float e = expf(s_l[tid][d] - m);
        s_l[tid][d] = e;
        sum += e;
      }
      float r = 1.f / sum;
      for (int d = 0; d < Cdim; ++d) s_l[tid][d] *= r;
    }
    __syncthreads();
    for (int idx = tid; idx < Cdim * Kdim; idx += 256) {
      int c = idx >> 3, j = idx & 7;
      float o = 0.f;
      for (int d = 0; d < Cdim; ++d) o = fmaf(s_l[c][d], v_l[j][d], o);
      q_l[j][c] = o + f_l[j][c];  // residual, reuse q_l as t
    }
    __syncthreads();
    if (tid < Kdim) {
      int j = tid;
      float mu = 0.f;
      for (int c = 0; c < Cdim; ++c) mu += q_l[j][c];
      mu *= (1.f / Cdim);
      float var = 0.f;
      for (int c = 0; c < Cdim; ++c) {
        float d = q_l[j][c] - mu;
        var += d * d;
      }
      var *= (1.f / Cdim);
      float rs = rsqrtf(var + 1e-6f);
      for (int c = 0; c < Cdim; ++c) f_l[j][c] = (q_l[j][c] - mu) * rs * ln_w[c] + ln_b[c];
    }
  }
  __syncthreads();
  if (tid < Cdim) {
    int c = tid;
    float S1 = 0.f, S2c = 0.f;
#pragma unroll
    for (int j = 0; j < Kdim; ++j) {
      float pl = pooled[(b * Cdim + c) * Kdim + j];
      float fe = f_l[j][c];
      feat[(b * Cdim + c) * Kdim + j] = fe;
      S1 += pl + cnt_raw[j] * fe;
      S2c += 2.f * pl * fe + cnt_raw[j] * fe * fe;
    }
    float S2 = sxx[b * Cdim + c] + S2c;
    float mu = S1 * (1.f / Ndim);
    float var = S2 * (1.f / Ndim) - mu * mu;
    float rs = rsqrtf(var + 1e-5f);
    mu_i[b * Cdim + c] = mu;
    rs_i[b * Cdim + c] = rs;
    ratio[b * Cdim + c] = var * rs * rs;  // var/(var+eps) for batch-norm var
  }
}

// ---------------- kernel 4: fold instance+batch norm into per-(b,c) affine -----
__global__ void k_alpha(const float* __restrict__ mu_i, const float* __restrict__ rs_i,
                        const float* __restrict__ ratio, const float* __restrict__ bn_w,
                        const float* __restrict__ bn_b, float* __restrict__ alpha,
                        float* __restrict__ beta) {
  int c = threadIdx.x;  // 128 threads, 1 block
  float vb = 0.f;
  for (int b = 0; b < Bdim; ++b) vb += ratio[b * Cdim + c];
  vb *= (1.f / Bdim);
  float rsb = rsqrtf(vb + 1e-5f);   // batch-norm mean is exactly 0
  float w = bn_w[c], bb = bn_b[c];
  for (int b = 0; b < Bdim; ++b) {
    float a = rs_i[b * Cdim + c] * rsb * w;
    alpha[b * Cdim + c] = a;
    beta[b * Cdim + c] = bb - mu_i[b * Cdim + c] * a;
  }
}

// ---------------- kernel 5: transpose conv0_w once -----------------------------
__global__ void k_transpose(const float* __restrict__ W, float* __restrict__ Wt) {
  int idx = blockIdx.x * 256 + threadIdx.x;  // 16384
  int o = idx >> 7, c = idx & 127;
  Wt[c * Cdim + o] = W[idx];
}

// ---------------- kernel 6: per-(b,c) mean of GELU'd activations ---------------
// mean_n gelu(alpha*recon+beta) -> gmean[b*C+c]; feeds SE path via linearity:
// mean_n conv[b,o,:] = sum_c W[o][c]*gmean[b,c] + bias[o]
__global__ void __launch_bounds__(256) k_gmean(
    const float* __restrict__ x, const signed char* __restrict__ kbin,
    const float* __restrict__ feat, const float* __restrict__ alpha,
    const float* __restrict__ beta, float* __restrict__ gmean) {
  int bc = blockIdx.x;
  int b = bc >> 7;
  __shared__ float fl[Kdim];
  int tid = threadIdx.x;
  if (tid < Kdim) fl[tid] = feat[bc * Kdim + tid];
  __syncthreads();
  float a = alpha[bc], be = beta[bc];
  const float4* xr = (const float4*)(x + (size_t)bc * Ndim);
  const char4* kr = (const char4*)(kbin + b * Ndim);
  float s = 0.f;
  for (int n4 = tid; n4 < Ndim / 4; n4 += 256) {
    float4 v = xr[n4];
    char4 kb = kr[n4];
    float ve[4] = {v.x, v.y, v.z, v.w};
    signed char ke[4] = {kb.x, kb.y, kb.z, kb.w};
#pragma unroll
    for (int e = 0; e < 4; ++e) {
      int kv = ke[e];
      float rec = 0.f;
#pragma unroll
      for (int j = 0; j < Kdim; ++j) rec += (kv == j) ? (ve[e] + fl[j]) : 0.f;
      float h = fmaf(a, rec, be);
      s += 0.5f * h * (1.0f + erff(h * 0.7071067811865475244f));
    }
  }
#pragma unroll
  for (int off = 32; off > 0; off >>= 1) s += __shfl_down(s, off);
  __shared__ float red[4];
  int wv = tid >> 6;
  if ((tid & 63) == 0) red[wv] = s;
  __syncthreads();
  if (tid == 0) gmean[bc] = (red[0] + red[1] + red[2] + red[3]) * (1.0f / Ndim);
}

// ---------------- kernel 7: SE MLP from gmean (linearity) ----------------------
__global__ void __launch_bounds__(128) k_mlp(const float* __restrict__ gmean,
                                             const float* __restrict__ W,      // conv0_w [o][c]
                                             const float* __restrict__ conv_b,
                                             const float* __restrict__ fc1w,
                                             const float* __restrict__ fc1b,
                                             const float* __restrict__ fc2w,
                                             const float* __restrict__ fc2b,
                                             float* __restrict__ f2g) {
  __shared__ float gm[Cdim];
  __shared__ float sq[Cdim];
  __shared__ float f1[64];
  int b = blockIdx.x, tid = threadIdx.x;  // 128 threads
  gm[tid] = gmean[b * Cdim + tid];
  __syncthreads();
  float a = conv_b[tid];
  const float* wr = W + tid * Cdim;
  for (int c = 0; c < Cdim; ++c) a = fmaf(wr[c], gm[c], a);
  sq[tid] = a;
  __syncthreads();
  if (tid < 64) {
    float a1 = fc1b[tid];
    for (int c = 0; c < Cdim; ++c) a1 = fmaf(fc1w[tid * Cdim + c], sq[c], a1);
    f1[tid] = 0.5f * a1 * (1.0f + erff(a1 * 0.7071067811865475244f));
  }
  __syncthreads();
  float a2 = fc2b[tid];
  for (int i = 0; i < 64; ++i) a2 = fmaf(fc2w[tid * 64 + i], f1[i], a2);
  f2g[b * Cdim + tid] = 1.0f / (1.0f + expf(-a2));
}

// ---------------- kernel 8: fused recon+norm+gelu+conv+scale (main pass) -------
// LDS ~70KB -> 2 blocks/CU (vs 133KB/1 block before). W read from global
// (ty-uniform broadcast addresses, L1/L2-served, ~64MB L2 traffic total).
__global__ void __launch_bounds__(256) k_conv(
    const float* __restrict__ x, const signed char* __restrict__ kbin,
    const float* __restrict__ feat, const float* __restrict__ alpha,
    const float* __restrict__ beta, const float* __restrict__ Wt,  // [c][o]
    const float* __restrict__ bias, const float* __restrict__ f2g,
    float* __restrict__ out) {
  __shared__ float g_l[Cdim][Cdim];  // activations: g_l[c][n_local]  (64KB)
  __shared__ float feat_l[Cdim][Kdim];
  __shared__ float al_l[Cdim], be_l[Cdim], f2_l[Cdim], bi_l[Cdim];
  __shared__ signed char kb_l[128];
  int bx = blockIdx.x;
  int b = bx >> 7, nb = bx & 127;
  int n0 = nb * 128;
  int tid = threadIdx.x;
  for (int idx = tid; idx < Cdim * Kdim; idx += 256)
    ((float*)feat_l)[idx] = feat[b * Cdim * Kdim + idx];
  if (tid < Cdim) {
    al_l[tid] = alpha[b * Cdim + tid];
    be_l[tid] = beta[b * Cdim + tid];
    f2_l[tid] = f2g[b * Cdim + tid];
    bi_l[tid] = bias[tid];
  }
  if (tid < 128) kb_l[tid] = kbin[b * Ndim + n0 + tid];
  __syncthreads();
  // stage gelu'd activations
  for (int idx = tid; idx < Cdim * 32; idx += 256) {
    int c = idx >> 5, q4 = idx & 31;
    float4 xv = *(const float4*)(x + ((size_t)(b * Cdim + c)) * Ndim + n0 + q4 * 4);
    float a = al_l[c], be = be_l[c];
    float xe[4] = {xv.x, xv.y, xv.z, xv.w};
    float r[4];
#pragma unroll
    for (int e = 0; e < 4; ++e) {
      int kb = kb_l[q4 * 4 + e];
      float rec = (kb >= 0) ? (xe[e] + feat_l[c][kb]) : 0.0f;
      float h = fmaf(a, rec, be);
      r[e] = 0.5f * h * (1.0f + erff(h * 0.7071067811865475244f));
    }
    *(float4*)&g_l[c][q4 * 4] = make_float4(r[0], r[1], r[2], r[3]);
  }
  __syncthreads();
  int tx = tid & 15, ty = tid >> 4;
  float acc[8][8];
#pragma unroll
  for (int i = 0; i < 8; ++i)
#pragma unroll
    for (int j = 0; j < 8; ++j) acc[i][j] = 0.f;
  const float* wp = Wt + ty * 8;  // [c][o], stride Cdim; uniform across tx
#pragma unroll 4
  for (int c = 0; c < Cdim; ++c) {
    float4 a0 = *(const float4*)(wp + c * Cdim);
    float4 a1 = *(const float4*)(wp + c * Cdim + 4);
    float4 b0 = *(const float4*)&g_l[c][tx * 4];
    float4 b1 = *(const float4*)&g_l[c][tx * 4 + 64];
    float av[8] = {a0.x, a0.y, a0.z, a0.w, a1.x, a1.y, a1.z, a1.w};
    float bv[8] = {b0.x, b0.y, b0.z, b0.w, b1.x, b1.y, b1.z, b1.w};
#pragma unroll
    for (int i = 0; i < 8; ++i)
#pragma unroll
      for (int j = 0; j < 8; ++j) acc[i][j] = fmaf(av[i], bv[j], acc[i][j]);
  }
#pragma unroll
  for (int i = 0; i < 8; ++i) {
    int o = ty * 8 + i;
    float bo = bi_l[o];
    float sc = f2_l[o];
#pragma unroll
    for (int j = 0; j < 8; ++j) acc[i][j] = (acc[i][j] + bo) * sc;
    float* orow = out + ((size_t)(b * Cdim + o)) * Ndim + n0;
    *(float4*)(orow + tx * 4) = make_float4(acc[i][0], acc[i][1], acc[i][2], acc[i][3]);
    *(float4*)(orow + 64 + tx * 4) = make_float4(acc[i][4], acc[i][5], acc[i][6], acc[i][7]);
  }
}

extern "C" void kernel_launch(void* const* d_in, const int* in_sizes, int n_in,
                              void* d_out, int out_size, void* d_ws, size_t ws_size,
                              hipStream_t stream) {
  const float* x = (const float*)d_in[0];
  const float* logits = (const float*)d_in[1];
  const float* Wq1 = (const float*)d_in[2];
  const float* Wk1 = (const float*)d_in[3];
  const float* Wv1 = (const float*)d_in[4];
  const float* Wq2 = (const float*)d_in[5];
  const float* Wk2 = (const float*)d_in[6];
  const float* Wv2 = (const float*)d_in[7];
  const float* Wq3 = (const float*)d_in[8];
  const float* Wk3 = (const float*)d_in[9];
  const float* Wv3 = (const float*)d_in[10];
  const float* ln_w = (const float*)d_in[11];
  const float* ln_b = (const float*)d_in[12];
  const float* conv0_w = (const float*)d_in[13];
  const float* conv0_b = (const float*)d_in[14];
  const float* bn_w = (const float*)d_in[15];
  const float* bn_b = (const float*)d_in[16];
  const float* fc1_w = (const float*)d_in[17];
  const float* fc1_b = (const float*)d_in[18];
  const float* fc2_w = (const float*)d_in[19];
  const float* fc2_b = (const float*)d_in[20];
  float* out = (float*)d_out;

  char* p = (char*)d_ws;
  auto alloc = [&](size_t bytes) {
    char* r = p;
    p += (bytes + 255) & ~(size_t)255;
    return r;
  };
  signed char* kbin = (signed char*)alloc(Bdim * Ndim);
  int* cnt = (int*)alloc(Bdim * Kdim * 4);
  float* pooled = (float*)alloc(Bdim * Cdim * Kdim * 4);
  float* sxx = (float*)alloc(Bdim * Cdim * 4);
  float* feat = (float*)alloc(Bdim * Cdim * Kdim * 4);
  float* mu_i = (float*)alloc(Bdim * Cdim * 4);
  float* rs_i = (float*)alloc(Bdim * Cdim * 4);
  float* ratio = (float*)alloc(Bdim * Cdim * 4);
  float* alpha = (float*)alloc(Bdim * Cdim * 4);
  float* beta = (float*)alloc(Bdim * Cdim * 4);
  float* Wt = (float*)alloc(Cdim * Cdim * 4);
  float* f2g = (float*)alloc(Bdim * Cdim * 4);
  float* gmean = (float*)alloc(Bdim * Cdim * 4);

  hipMemsetAsync(cnt, 0, Bdim * Kdim * sizeof(int), stream);
  k_bin<<<Bdim * Ndim / 256, 256, 0, stream>>>(logits, kbin, cnt);
  k_transpose<<<Cdim * Cdim / 256, 256, 0, stream>>>(conv0_w, Wt);
  k_pool<<<Bdim * Cdim, 256, 0, stream>>>(x, kbin, pooled, sxx);
  k_xform<<<Bdim, 256, 0, stream>>>(pooled, cnt, sxx, Wq1, Wk1, Wv1, Wq2, Wk2, Wv2,
                                    Wq3, Wk3, Wv3, ln_w, ln_b, feat, mu_i, rs_i, ratio);
  k_alpha<<<1, 128, 0, stream>>>(mu_i, rs_i, ratio, bn_w, bn_b, alpha, beta);
  k_gmean<<<Bdim * Cdim, 256, 0, stream>>>(x, kbin, feat, alpha, beta, gmean);
  k_mlp<<<Bdim, 128, 0, stream>>>(gmean, conv0_w, conv0_b, fc1_w, fc1_b, fc2_w, fc2_b, f2g);
  k_conv<<<Bdim * (Ndim / 128), 256, 0, stream>>>(x, kbin, feat, alpha, beta, Wt,
                                                  conv0_b, f2g, out);
}

// Round 3
// 275.625 us; speedup vs baseline: 1.2386x; 1.0436x over previous
//
#include <hip/hip_runtime.h>
#include <math.h>

#define Bdim 8
#define Cdim 128
#define Ndim 16384
#define Kdim 8

// ---------------- kernel 1: bin assignment + counts ----------------
__global__ void __launch_bounds__(256) k_bin(const float* __restrict__ logits,
                                             signed char* __restrict__ kbin,
                                             int* __restrict__ cnt) {
  __shared__ int h[Kdim];
  int tid = threadIdx.x;
  if (tid < Kdim) h[tid] = 0;
  __syncthreads();
  int idx = blockIdx.x * 256 + tid;              // < B*N, block stays in one b
  int b = idx >> 14;                             // /16384
  float w = tanhf(logits[idx]);
  int kb = -1;
#pragma unroll
  for (int j = 0; j < Kdim; ++j) {
    float lo = -1.0f + 0.25f * (float)j;
    float hi = lo + 0.25f;
    if (w > lo && w <= hi && w != 0.0f) kb = j;
  }
  kbin[idx] = (signed char)kb;
  if (kb >= 0) atomicAdd(&h[kb], 1);
  __syncthreads();
  if (tid < Kdim) atomicAdd(&cnt[b * Kdim + tid], h[tid]);
}

// ---------------- kernel 2: per-(b,c) masked pooling + masked sum of squares ----
__global__ void __launch_bounds__(256) k_pool(const float* __restrict__ x,
                                              const signed char* __restrict__ kbin,
                                              float* __restrict__ pooled,
                                              float* __restrict__ sxx) {
  int bc = blockIdx.x;                 // b*C + c
  int b = bc >> 7;
  const float4* xr = (const float4*)(x + (size_t)bc * Ndim);
  const char4* kr = (const char4*)(kbin + b * Ndim);
  float acc[Kdim];
#pragma unroll
  for (int j = 0; j < Kdim; ++j) acc[j] = 0.f;
  float s2 = 0.f;
  int tid = threadIdx.x;
  for (int n4 = tid; n4 < Ndim / 4; n4 += 256) {
    float4 v = xr[n4];
    char4 kb = kr[n4];
    float ve[4] = {v.x, v.y, v.z, v.w};
    signed char ke[4] = {kb.x, kb.y, kb.z, kb.w};
#pragma unroll
    for (int e = 0; e < 4; ++e) {
      float xv = ve[e];
      int kv = ke[e];
      if (kv >= 0) s2 += xv * xv;
#pragma unroll
      for (int j = 0; j < Kdim; ++j) acc[j] += (kv == j) ? xv : 0.f;
    }
  }
#pragma unroll
  for (int off = 32; off > 0; off >>= 1) {
#pragma unroll
    for (int j = 0; j < Kdim; ++j) acc[j] += __shfl_down(acc[j], off);
    s2 += __shfl_down(s2, off);
  }
  __shared__ float red[4][Kdim + 1];
  int wv = tid >> 6, ln = tid & 63;
  if (ln == 0) {
#pragma unroll
    for (int j = 0; j < Kdim; ++j) red[wv][j] = acc[j];
    red[wv][Kdim] = s2;
  }
  __syncthreads();
  if (tid < Kdim) pooled[bc * Kdim + tid] = red[0][tid] + red[1][tid] + red[2][tid] + red[3][tid];
  if (tid == Kdim) sxx[bc] = red[0][Kdim] + red[1][Kdim] + red[2][Kdim] + red[3][Kdim];
}

// ---------------- kernel 3: 3-layer transformer, 1024 threads, LDS-staged W ----
// Wl (64KB, padded rows of 132 floats) is reused: staged weight matrix during
// projections, then the 128x128 score/attention matrix. Pad=132 -> rows offset
// by 4 banks -> no stride-128 bank conflicts on row-parallel reads.
__global__ void __launch_bounds__(1024) k_xform(
    const float* __restrict__ pooled, const int* __restrict__ cnt,
    const float* __restrict__ sxx,
    const float* __restrict__ Wq1, const float* __restrict__ Wk1, const float* __restrict__ Wv1,
    const float* __restrict__ Wq2, const float* __restrict__ Wk2, const float* __restrict__ Wv2,
    const float* __restrict__ Wq3, const float* __restrict__ Wk3, const float* __restrict__ Wv3,
    const float* __restrict__ ln_w, const float* __restrict__ ln_b,
    float* __restrict__ feat, float* __restrict__ mu_i, float* __restrict__ rs_i,
    float* __restrict__ ratio) {
  __shared__ float Wl[Cdim][132];
  __shared__ float f_l[Kdim][Cdim], q_l[Kdim][Cdim], kk_l[Kdim][Cdim], v_l[Kdim][Cdim];
  __shared__ float lnw_l[Cdim], lnb_l[Cdim];
  __shared__ float cnt_raw[Kdim], cnt_div[Kdim];
  __shared__ float redA[Kdim][2], redB[Kdim][2];
  int b = blockIdx.x, tid = threadIdx.x;
  if (tid < Kdim) {
    int cc = cnt[b * Kdim + tid];
    cnt_raw[tid] = (float)cc;
    cnt_div[tid] = (float)(cc == 0 ? 1 : cc);
  }
  if (tid >= 128 && tid < 256) lnw_l[tid - 128] = ln_w[tid - 128];
  if (tid >= 256 && tid < 384) lnb_l[tid - 256] = ln_b[tid - 256];
  __syncthreads();
  {  // load f (1024 = C*K items, one per thread)
    int c = tid >> 3, j = tid & 7;
    f_l[j][c] = pooled[(b * Cdim + c) * Kdim + j] / cnt_div[j];
  }
  const float* Wq[3] = {Wq1, Wq2, Wq3};
  const float* Wk[3] = {Wk1, Wk2, Wk3};
  const float* Wv[3] = {Wv1, Wv2, Wv3};
  const float inv_temp = 0.08838834764831845f;  // 1/sqrt(128)
  for (int layer = 0; layer < 3; ++layer) {
    // ---- three projections, one staged W at a time ----
    for (int m = 0; m < 3; ++m) {
      const float* Wsrc = (m == 0) ? Wq[layer] : (m == 1) ? Wk[layer] : Wv[layer];
      __syncthreads();  // previous consumer of Wl done
#pragma unroll
      for (int k = 0; k < 4; ++k) {
        int idx = tid + k * 1024;  // 0..4095 float4s
        int r = idx >> 5, q = idx & 31;
        *(float4*)&Wl[r][q * 4] = ((const float4*)Wsrc)[idx];
      }
      __syncthreads();
      int o = tid >> 3, j = tid & 7;
      float acc = 0.f;
#pragma unroll 8
      for (int d4 = 0; d4 < 32; ++d4) {
        float4 w4 = *(const float4*)&Wl[o][d4 * 4];
        float4 f4 = *(const float4*)&f_l[j][d4 * 4];
        acc = fmaf(w4.x, f4.x, acc);
        acc = fmaf(w4.y, f4.y, acc);
        acc = fmaf(w4.z, f4.z, acc);
        acc = fmaf(w4.w, f4.w, acc);
      }
      if (m == 0) q_l[j][o] = acc * inv_temp;
      else if (m == 1) kk_l[j][o] = acc;
      else v_l[j][o] = acc;
    }
    __syncthreads();
    // ---- scores + softmax into Wl: thread -> (c = tid>>3, 16 d's) ----
    {
      int c = tid >> 3, d0 = (tid & 7) * 16;
      float qv[8];
#pragma unroll
      for (int j = 0; j < 8; ++j) qv[j] = q_l[j][c];
      float sv[16];
#pragma unroll
      for (int dd = 0; dd < 16; ++dd) {
        int d = d0 + dd;
        float s = 0.f;
#pragma unroll
        for (int j = 0; j < 8; ++j) s = fmaf(qv[j], kk_l[j][d], s);
        sv[dd] = s;
      }
      float m = -1e30f;
#pragma unroll
      for (int dd = 0; dd < 16; ++dd) m = fmaxf(m, sv[dd]);
      m = fmaxf(m, __shfl_xor(m, 1));
      m = fmaxf(m, __shfl_xor(m, 2));
      m = fmaxf(m, __shfl_xor(m, 4));
      float sum = 0.f;
#pragma unroll
      for (int dd = 0; dd < 16; ++dd) {
        float e = expf(sv[dd] - m);
        sv[dd] = e;
        sum += e;
      }
      sum += __shfl_xor(sum, 1);
      sum += __shfl_xor(sum, 2);
      sum += __shfl_xor(sum, 4);
      float r = 1.f / sum;
#pragma unroll
      for (int q4 = 0; q4 < 4; ++q4)
        *(float4*)&Wl[c][d0 + q4 * 4] = make_float4(sv[q4 * 4] * r, sv[q4 * 4 + 1] * r,
                                                    sv[q4 * 4 + 2] * r, sv[q4 * 4 + 3] * r);
    }
    __syncthreads();
    // ---- PV + residual -> q_l (as temp t) ----
    {
      int c = tid >> 3, j = tid & 7;
      float acc = 0.f;
#pragma unroll 8
      for (int d4 = 0; d4 < 32; ++d4) {
        float4 s4 = *(const float4*)&Wl[c][d4 * 4];
        float4 v4 = *(const float4*)&v_l[j][d4 * 4];
        acc = fmaf(s4.x, v4.x, acc);
        acc = fmaf(s4.y, v4.y, acc);
        acc = fmaf(s4.z, v4.z, acc);
        acc = fmaf(s4.w, v4.w, acc);
      }
      float t = acc + f_l[j][c];
      __syncthreads();         // scores-phase readers of q_l are done (sync above)
      q_l[j][c] = t;
    }
    __syncthreads();
    // ---- LayerNorm over c per j: row j = 2 consecutive waves ----
    {
      int j = tid >> 7, c = tid & 127;
      float t = q_l[j][c];
      float s1 = t, s2 = t * t;
#pragma unroll
      for (int off = 32; off > 0; off >>= 1) {
        s1 += __shfl_xor(s1, off);
        s2 += __shfl_xor(s2, off);
      }
      int wv = (tid >> 6) & 1;
      if ((tid & 63) == 0) { redA[j][wv] = s1; redB[j][wv] = s2; }
      __syncthreads();
      float S1 = redA[j][0] + redA[j][1];
      float S2 = redB[j][0] + redB[j][1];
      float mu = S1 * (1.f / Cdim);
      float var = S2 * (1.f / Cdim) - mu * mu;
      float rs = rsqrtf(var + 1e-6f);
      f_l[j][c] = (t - mu) * rs * lnw_l[c] + lnb_l[c];
    }
    __syncthreads();
  }
  // ---- closed-form instance-norm stats ----
  if (tid < Cdim) {
    int c = tid;
    float S1 = 0.f, S2c = 0.f;
#pragma unroll
    for (int j = 0; j < Kdim; ++j) {
      float pl = pooled[(b * Cdim + c) * Kdim + j];
      float fe = f_l[j][c];
      feat[(b * Cdim + c) * Kdim + j] = fe;
      S1 += pl + cnt_raw[j] * fe;
      S2c += 2.f * pl * fe + cnt_raw[j] * fe * fe;
    }
    float S2 = sxx[b * Cdim + c] + S2c;
    float mu = S1 * (1.f / Ndim);
    float var = S2 * (1.f / Ndim) - mu * mu;
    float rs = rsqrtf(var + 1e-5f);
    mu_i[b * Cdim + c] = mu;
    rs_i[b * Cdim + c] = rs;
    ratio[b * Cdim + c] = var * rs * rs;  // var/(var+eps) for batch-norm var
  }
}

// ---------------- kernel 4: fold instance+batch norm into per-(b,c) affine -----
__global__ void k_alpha(const float* __restrict__ mu_i, const float* __restrict__ rs_i,
                        const float* __restrict__ ratio, const float* __restrict__ bn_w,
                        const float* __restrict__ bn_b, float* __restrict__ alpha,
                        float* __restrict__ beta) {
  int c = threadIdx.x;  // 128 threads, 1 block
  float vb = 0.f;
  for (int b = 0; b < Bdim; ++b) vb += ratio[b * Cdim + c];
  vb *= (1.f / Bdim);
  float rsb = rsqrtf(vb + 1e-5f);   // batch-norm mean is exactly 0
  float w = bn_w[c], bb = bn_b[c];
  for (int b = 0; b < Bdim; ++b) {
    float a = rs_i[b * Cdim + c] * rsb * w;
    alpha[b * Cdim + c] = a;
    beta[b * Cdim + c] = bb - mu_i[b * Cdim + c] * a;
  }
}

// ---------------- kernel 5: transpose conv0_w once -----------------------------
__global__ void k_transpose(const float* __restrict__ W, float* __restrict__ Wt) {
  int idx = blockIdx.x * 256 + threadIdx.x;  // 16384
  int o = idx >> 7, c = idx & 127;
  Wt[c * Cdim + o] = W[idx];
}

// ---------------- kernel 6: per-(b,c) mean of GELU'd activations ---------------
__global__ void __launch_bounds__(256) k_gmean(
    const float* __restrict__ x, const signed char* __restrict__ kbin,
    const float* __restrict__ feat, const float* __restrict__ alpha,
    const float* __restrict__ beta, float* __restrict__ gmean) {
  int bc = blockIdx.x;
  int b = bc >> 7;
  __shared__ float fl[Kdim];
  int tid = threadIdx.x;
  if (tid < Kdim) fl[tid] = feat[bc * Kdim + tid];
  __syncthreads();
  float a = alpha[bc], be = beta[bc];
  const float4* xr = (const float4*)(x + (size_t)bc * Ndim);
  const char4* kr = (const char4*)(kbin + b * Ndim);
  float s = 0.f;
  for (int n4 = tid; n4 < Ndim / 4; n4 += 256) {
    float4 v = xr[n4];
    char4 kb = kr[n4];
    float ve[4] = {v.x, v.y, v.z, v.w};
    signed char ke[4] = {kb.x, kb.y, kb.z, kb.w};
#pragma unroll
    for (int e = 0; e < 4; ++e) {
      int kv = ke[e];
      float rec = 0.f;
#pragma unroll
      for (int j = 0; j < Kdim; ++j) rec += (kv == j) ? (ve[e] + fl[j]) : 0.f;
      float h = fmaf(a, rec, be);
      s += 0.5f * h * (1.0f + erff(h * 0.7071067811865475244f));
    }
  }
#pragma unroll
  for (int off = 32; off > 0; off >>= 1) s += __shfl_down(s, off);
  __shared__ float red[4];
  int wv = tid >> 6;
  if ((tid & 63) == 0) red[wv] = s;
  __syncthreads();
  if (tid == 0) gmean[bc] = (red[0] + red[1] + red[2] + red[3]) * (1.0f / Ndim);
}

// ---------------- kernel 7: SE MLP from gmean (linearity) ----------------------
__global__ void __launch_bounds__(128) k_mlp(const float* __restrict__ gmean,
                                             const float* __restrict__ W,      // conv0_w [o][c]
                                             const float* __restrict__ conv_b,
                                             const float* __restrict__ fc1w,
                                             const float* __restrict__ fc1b,
                                             const float* __restrict__ fc2w,
                                             const float* __restrict__ fc2b,
                                             float* __restrict__ f2g) {
  __shared__ float gm[Cdim];
  __shared__ float sq[Cdim];
  __shared__ float f1[64];
  int b = blockIdx.x, tid = threadIdx.x;  // 128 threads
  gm[tid] = gmean[b * Cdim + tid];
  __syncthreads();
  float a = conv_b[tid];
  const float* wr = W + tid * Cdim;
  for (int c = 0; c < Cdim; ++c) a = fmaf(wr[c], gm[c], a);
  sq[tid] = a;
  __syncthreads();
  if (tid < 64) {
    float a1 = fc1b[tid];
    for (int c = 0; c < Cdim; ++c) a1 = fmaf(fc1w[tid * Cdim + c], sq[c], a1);
    f1[tid] = 0.5f * a1 * (1.0f + erff(a1 * 0.7071067811865475244f));
  }
  __syncthreads();
  float a2 = fc2b[tid];
  for (int i = 0; i < 64; ++i) a2 = fmaf(fc2w[tid * 64 + i], f1[i], a2);
  f2g[b * Cdim + tid] = 1.0f / (1.0f + expf(-a2));
}

// ---------------- kernel 8: fused recon+norm+gelu+conv+scale (main pass) -------
// 512 threads, 8x4 acc/thread -> ~80 VGPR, LDS ~70KB -> 2 blocks/CU = 16 waves.
__global__ void __launch_bounds__(512) k_conv(
    const float* __restrict__ x, const signed char* __restrict__ kbin,
    const float* __restrict__ feat, const float* __restrict__ alpha,
    const float* __restrict__ beta, const float* __restrict__ Wt,  // [c][o]
    const float* __restrict__ bias, const float* __restrict__ f2g,
    float* __restrict__ out) {
  __shared__ float g_l[Cdim][Cdim];  // activations: g_l[c][n_local]  (64KB)
  __shared__ float feat_l[Cdim][Kdim];
  __shared__ float al_l[Cdim], be_l[Cdim], f2_l[Cdim], bi_l[Cdim];
  __shared__ signed char kb_l[128];
  int bx = blockIdx.x;
  int b = bx >> 7, nb = bx & 127;
  int n0 = nb * 128;
  int tid = threadIdx.x;
  for (int idx = tid; idx < Cdim * Kdim; idx += 512)
    ((float*)feat_l)[idx] = feat[b * Cdim * Kdim + idx];
  if (tid < Cdim) {
    al_l[tid] = alpha[b * Cdim + tid];
    be_l[tid] = beta[b * Cdim + tid];
    f2_l[tid] = f2g[b * Cdim + tid];
    bi_l[tid] = bias[tid];
  }
  if (tid >= 256 && tid < 384) kb_l[tid - 256] = kbin[b * Ndim + n0 + (tid - 256)];
  __syncthreads();
  // stage gelu'd activations
  for (int idx = tid; idx < Cdim * 32; idx += 512) {
    int c = idx >> 5, q4 = idx & 31;
    float4 xv = *(const float4*)(x + ((size_t)(b * Cdim + c)) * Ndim + n0 + q4 * 4);
    float a = al_l[c], be = be_l[c];
    float xe[4] = {xv.x, xv.y, xv.z, xv.w};
    float r[4];
#pragma unroll
    for (int e = 0; e < 4; ++e) {
      int kb = kb_l[q4 * 4 + e];
      float rec = (kb >= 0) ? (xe[e] + feat_l[c][kb]) : 0.0f;
      float h = fmaf(a, rec, be);
      r[e] = 0.5f * h * (1.0f + erff(h * 0.7071067811865475244f));
    }
    *(float4*)&g_l[c][q4 * 4] = make_float4(r[0], r[1], r[2], r[3]);
  }
  __syncthreads();
  int tx = tid & 31, ty = tid >> 5;  // tx: 32 groups of 4 n; ty: 16 groups of 8 o
  float acc[8][4];
#pragma unroll
  for (int i = 0; i < 8; ++i)
#pragma unroll
    for (int j = 0; j < 4; ++j) acc[i][j] = 0.f;
  const float* wp = Wt + ty * 8;  // [c][o], stride Cdim; uniform across tx
#pragma unroll 2
  for (int c = 0; c < Cdim; ++c) {
    float4 a0 = *(const float4*)(wp + c * Cdim);
    float4 a1 = *(const float4*)(wp + c * Cdim + 4);
    float4 b0 = *(const float4*)&g_l[c][tx * 4];
    float av[8] = {a0.x, a0.y, a0.z, a0.w, a1.x, a1.y, a1.z, a1.w};
    float bv[4] = {b0.x, b0.y, b0.z, b0.w};
#pragma unroll
    for (int i = 0; i < 8; ++i)
#pragma unroll
      for (int j = 0; j < 4; ++j) acc[i][j] = fmaf(av[i], bv[j], acc[i][j]);
  }
#pragma unroll
  for (int i = 0; i < 8; ++i) {
    int o = ty * 8 + i;
    float bo = bi_l[o];
    float sc = f2_l[o];
    float* orow = out + ((size_t)(b * Cdim + o)) * Ndim + n0;
    *(float4*)(orow + tx * 4) = make_float4((acc[i][0] + bo) * sc, (acc[i][1] + bo) * sc,
                                            (acc[i][2] + bo) * sc, (acc[i][3] + bo) * sc);
  }
}

extern "C" void kernel_launch(void* const* d_in, const int* in_sizes, int n_in,
                              void* d_out, int out_size, void* d_ws, size_t ws_size,
                              hipStream_t stream) {
  const float* x = (const float*)d_in[0];
  const float* logits = (const float*)d_in[1];
  const float* Wq1 = (const float*)d_in[2];
  const float* Wk1 = (const float*)d_in[3];
  const float* Wv1 = (const float*)d_in[4];
  const float* Wq2 = (const float*)d_in[5];
  const float* Wk2 = (const float*)d_in[6];
  const float* Wv2 = (const float*)d_in[7];
  const float* Wq3 = (const float*)d_in[8];
  const float* Wk3 = (const float*)d_in[9];
  const float* Wv3 = (const float*)d_in[10];
  const float* ln_w = (const float*)d_in[11];
  const float* ln_b = (const float*)d_in[12];
  const float* conv0_w = (const float*)d_in[13];
  const float* conv0_b = (const float*)d_in[14];
  const float* bn_w = (const float*)d_in[15];
  const float* bn_b = (const float*)d_in[16];
  const float* fc1_w = (const float*)d_in[17];
  const float* fc1_b = (const float*)d_in[18];
  const float* fc2_w = (const float*)d_in[19];
  const float* fc2_b = (const float*)d_in[20];
  float* out = (float*)d_out;

  char* p = (char*)d_ws;
  auto alloc = [&](size_t bytes) {
    char* r = p;
    p += (bytes + 255) & ~(size_t)255;
    return r;
  };
  signed char* kbin = (signed char*)alloc(Bdim * Ndim);
  int* cnt = (int*)alloc(Bdim * Kdim * 4);
  float* pooled = (float*)alloc(Bdim * Cdim * Kdim * 4);
  float* sxx = (float*)alloc(Bdim * Cdim * 4);
  float* feat = (float*)alloc(Bdim * Cdim * Kdim * 4);
  float* mu_i = (float*)alloc(Bdim * Cdim * 4);
  float* rs_i = (float*)alloc(Bdim * Cdim * 4);
  float* ratio = (float*)alloc(Bdim * Cdim * 4);
  float* alpha = (float*)alloc(Bdim * Cdim * 4);
  float* beta = (float*)alloc(Bdim * Cdim * 4);
  float* Wt = (float*)alloc(Cdim * Cdim * 4);
  float* f2g = (float*)alloc(Bdim * Cdim * 4);
  float* gmean = (float*)alloc(Bdim * Cdim * 4);

  hipMemsetAsync(cnt, 0, Bdim * Kdim * sizeof(int), stream);
  k_bin<<<Bdim * Ndim / 256, 256, 0, stream>>>(logits, kbin, cnt);
  k_transpose<<<Cdim * Cdim / 256, 256, 0, stream>>>(conv0_w, Wt);
  k_pool<<<Bdim * Cdim, 256, 0, stream>>>(x, kbin, pooled, sxx);
  k_xform<<<Bdim, 1024, 0, stream>>>(pooled, cnt, sxx, Wq1, Wk1, Wv1, Wq2, Wk2, Wv2,
                                     Wq3, Wk3, Wv3, ln_w, ln_b, feat, mu_i, rs_i, ratio);
  k_alpha<<<1, 128, 0, stream>>>(mu_i, rs_i, ratio, bn_w, bn_b, alpha, beta);
  k_gmean<<<Bdim * Cdim, 256, 0, stream>>>(x, kbin, feat, alpha, beta, gmean);
  k_mlp<<<Bdim, 128, 0, stream>>>(gmean, conv0_w, conv0_b, fc1_w, fc1_b, fc2_w, fc2_b, f2g);
  k_conv<<<Bdim * (Ndim / 128), 512, 0, stream>>>(x, kbin, feat, alpha, beta, Wt,
                                                  conv0_b, f2g, out);
}